// Round 1
// baseline (584.193 us; speedup 1.0000x reference)
//
#include <hip/hip_runtime.h>
#include <hip/hip_bf16.h>

#define DDIM 64

using bf16x8 = __attribute__((ext_vector_type(8))) short;
using f32x4  = __attribute__((ext_vector_type(4))) float;

__device__ inline unsigned short f2bf(float f) {
  union { float f; unsigned u; } v; v.f = f;
  unsigned u = v.u + 0x7fffu + ((v.u >> 16) & 1u);  // RNE
  return (unsigned short)(u >> 16);
}
__device__ inline float bf2f(unsigned short h) {
  union { float f; unsigned u; } v; v.u = ((unsigned)h) << 16; return v.f;
}

// Convert fp32 rows -> bf16 rows, compute per-row sum of squares (of the
// bf16-rounded values, so the GEMM identity is exact for the rounded vectors).
// 16 lanes per row, 4 elems (one float4) per lane.
__global__ __launch_bounds__(256) void prep_kernel(
    const float* __restrict__ x, const float* __restrict__ y,
    unsigned short* __restrict__ xb, unsigned short* __restrict__ yb,
    float* __restrict__ xn, float* __restrict__ yn, int M, int N) {
  int tid = threadIdx.x;
  int row = blockIdx.x * 16 + (tid >> 4);
  int l   = tid & 15;
  const float* src; unsigned short* dst; float* nrm;
  if (row < M) {
    src = x + (size_t)row * DDIM; dst = xb + (size_t)row * DDIM; nrm = xn + row;
  } else {
    int r = row - M;
    if (r >= N) return;
    src = y + (size_t)r * DDIM; dst = yb + (size_t)r * DDIM; nrm = yn + r;
  }
  float4 v = *(const float4*)(src + l * 4);
  unsigned short b0 = f2bf(v.x), b1 = f2bf(v.y), b2 = f2bf(v.z), b3 = f2bf(v.w);
  float f0 = bf2f(b0), f1 = bf2f(b1), f2 = bf2f(b2), f3 = bf2f(b3);
  ushort4 s; s.x = b0; s.y = b1; s.z = b2; s.w = b3;
  *(ushort4*)(dst + l * 4) = s;
  float acc = f0 * f0 + f1 * f1 + f2 * f2 + f3 * f3;
  #pragma unroll
  for (int m = 1; m < 16; m <<= 1) acc += __shfl_xor(acc, m, 16);
  if (l == 0) *nrm = acc;
}

// One block = 128(x) x 128(y) output tile, 4 waves in 2x2, each wave 64x64
// via 4x4 grid of 16x16x32 bf16 MFMAs, K=64 in two k-steps. No LDS.
//
// OPERANDS SWAPPED vs v0: A = y rows (MFMA-M), B = x rows (MFMA-N).
// C/D layout is col(=x row)=lane&15, row(=y col)=quad*4+reg, so each
// f32x4 fragment register quad holds out[xrow][ycol..ycol+3] -> one
// contiguous 16B global_store_dwordx4 per fragment per lane (16 stores
// per thread instead of 64 scalar stores: v0 was VMEM-issue bound).
__global__ __launch_bounds__(256) void cdist_mfma_kernel(
    const unsigned short* __restrict__ xb, const unsigned short* __restrict__ yb,
    const float* __restrict__ xn, const float* __restrict__ yn,
    float* __restrict__ out, int Ncols) {
  int ybase = blockIdx.x * 128;   // y rows = out columns
  int xbase = blockIdx.y * 128;   // x rows = out rows
  int tid = threadIdx.x, wave = tid >> 6, lane = tid & 63;
  int quad = lane >> 4, l16 = lane & 15;
  int wy = (wave >> 1) * 64;      // wave offset along y (MFMA-M)
  int wx = (wave & 1) * 64;       // wave offset along x (MFMA-N)

  const short* yp = (const short*)yb;
  const short* xp = (const short*)xb;
  int arow = ybase + wy + l16;    // A fragment rows come from y
  int brow = xbase + wx + l16;    // B fragment rows come from x
  int koff = quad * 8;

  bf16x8 a[2][4], b[2][4];
  #pragma unroll
  for (int i = 0; i < 4; i++) {
    const short* ap = yp + (size_t)(arow + i * 16) * DDIM + koff;
    const short* bp = xp + (size_t)(brow + i * 16) * DDIM + koff;
    a[0][i] = *(const bf16x8*)(ap);
    a[1][i] = *(const bf16x8*)(ap + 32);
    b[0][i] = *(const bf16x8*)(bp);
    b[1][i] = *(const bf16x8*)(bp + 32);
  }

  f32x4 acc[4][4] = {};
  #pragma unroll
  for (int ks = 0; ks < 2; ks++)
    #pragma unroll
    for (int i = 0; i < 4; i++)
      #pragma unroll
      for (int j = 0; j < 4; j++)
        acc[i][j] = __builtin_amdgcn_mfma_f32_16x16x32_bf16(
            a[ks][i], b[ks][j], acc[i][j], 0, 0, 0);

  // Epilogue: d = sqrt(max(xn + yn - 2*dot, 0)).
  // acc[i][j][r]: dot(y[ybase+wy+i*16+quad*4+r], x[xbase+wx+j*16+l16]).
  #pragma unroll
  for (int j = 0; j < 4; j++) {
    int xrow = xbase + wx + j * 16 + l16;
    float xv = xn[xrow];
    float* orow = out + (size_t)xrow * Ncols;
    #pragma unroll
    for (int i = 0; i < 4; i++) {
      int ycol = ybase + wy + i * 16 + quad * 4;
      float4 yv = *(const float4*)(yn + ycol);
      f32x4 d;
      d[0] = sqrtf(fmaxf(xv + yv.x - 2.0f * acc[i][j][0], 0.0f));
      d[1] = sqrtf(fmaxf(xv + yv.y - 2.0f * acc[i][j][1], 0.0f));
      d[2] = sqrtf(fmaxf(xv + yv.z - 2.0f * acc[i][j][2], 0.0f));
      d[3] = sqrtf(fmaxf(xv + yv.w - 2.0f * acc[i][j][3], 0.0f));
      *(f32x4*)(orow + ycol) = d;
    }
  }
}

// Correctness fallback if workspace is too small (shouldn't happen).
__global__ void cdist_naive_kernel(const float* __restrict__ x,
                                   const float* __restrict__ y,
                                   float* __restrict__ out, int M, int N) {
  size_t idx = (size_t)blockIdx.x * blockDim.x + threadIdx.x;
  size_t total = (size_t)M * N;
  if (idx >= total) return;
  int i = (int)(idx / N), j = (int)(idx % N);
  const float* xi = x + (size_t)i * DDIM;
  const float* yj = y + (size_t)j * DDIM;
  float acc = 0.f;
  #pragma unroll
  for (int k = 0; k < DDIM; k++) {
    float d = xi[k] - yj[k];
    acc += d * d;
  }
  out[idx] = sqrtf(acc);
}

extern "C" void kernel_launch(void* const* d_in, const int* in_sizes, int n_in,
                              void* d_out, int out_size, void* d_ws, size_t ws_size,
                              hipStream_t stream) {
  const float* x = (const float*)d_in[0];
  const float* y = (const float*)d_in[1];
  float* out = (float*)d_out;
  int M = in_sizes[0] / DDIM;   // 8192
  int N = in_sizes[1] / DDIM;   // 16384

  size_t xb_off = 0;
  size_t yb_off = xb_off + (size_t)M * DDIM * sizeof(unsigned short);
  size_t xn_off = yb_off + (size_t)N * DDIM * sizeof(unsigned short);
  size_t yn_off = xn_off + (size_t)M * sizeof(float);
  size_t need   = yn_off + (size_t)N * sizeof(float);

  if (ws_size < need || (M % 128) || (N % 128)) {
    size_t total = (size_t)M * N;
    int blocks = (int)((total + 255) / 256);
    cdist_naive_kernel<<<blocks, 256, 0, stream>>>(x, y, out, M, N);
    return;
  }

  unsigned short* xb = (unsigned short*)((char*)d_ws + xb_off);
  unsigned short* yb = (unsigned short*)((char*)d_ws + yb_off);
  float* xn = (float*)((char*)d_ws + xn_off);
  float* yn = (float*)((char*)d_ws + yn_off);

  int prep_blocks = (M + N) / 16;
  prep_kernel<<<prep_blocks, 256, 0, stream>>>(x, y, xb, yb, xn, yn, M, N);

  dim3 grid(N / 128, M / 128);
  cdist_mfma_kernel<<<grid, 256, 0, stream>>>(xb, yb, xn, yn, out, N);
}

// Round 2
// 552.011 us; speedup vs baseline: 1.0583x; 1.0583x over previous
//
#include <hip/hip_runtime.h>
#include <hip/hip_bf16.h>

#define DDIM 64

using bf16x8 = __attribute__((ext_vector_type(8))) short;
using f32x4  = __attribute__((ext_vector_type(4))) float;

__device__ inline unsigned short f2bf(float f) {
  union { float f; unsigned u; } v; v.f = f;
  unsigned u = v.u + 0x7fffu + ((v.u >> 16) & 1u);  // RNE
  return (unsigned short)(u >> 16);
}
__device__ inline float bf2f(unsigned short h) {
  union { float f; unsigned u; } v; v.u = ((unsigned)h) << 16; return v.f;
}

// Convert fp32 rows -> bf16 rows, compute per-row sum of squares (of the
// bf16-rounded values, so the GEMM identity is exact for the rounded vectors).
__global__ __launch_bounds__(256) void prep_kernel(
    const float* __restrict__ x, const float* __restrict__ y,
    unsigned short* __restrict__ xb, unsigned short* __restrict__ yb,
    float* __restrict__ xn, float* __restrict__ yn, int M, int N) {
  int tid = threadIdx.x;
  int row = blockIdx.x * 16 + (tid >> 4);
  int l   = tid & 15;
  const float* src; unsigned short* dst; float* nrm;
  if (row < M) {
    src = x + (size_t)row * DDIM; dst = xb + (size_t)row * DDIM; nrm = xn + row;
  } else {
    int r = row - M;
    if (r >= N) return;
    src = y + (size_t)r * DDIM; dst = yb + (size_t)r * DDIM; nrm = yn + r;
  }
  float4 v = *(const float4*)(src + l * 4);
  unsigned short b0 = f2bf(v.x), b1 = f2bf(v.y), b2 = f2bf(v.z), b3 = f2bf(v.w);
  float f0 = bf2f(b0), f1 = bf2f(b1), f2 = bf2f(b2), f3 = bf2f(b3);
  ushort4 s; s.x = b0; s.y = b1; s.z = b2; s.w = b3;
  *(ushort4*)(dst + l * 4) = s;
  float acc = f0 * f0 + f1 * f1 + f2 * f2 + f3 * f3;
  #pragma unroll
  for (int m = 1; m < 16; m <<= 1) acc += __shfl_xor(acc, m, 16);
  if (l == 0) *nrm = acc;
}

// One block = 128(x) x 128(y) output tile, 4 waves in 2x2, each wave 64x64
// via 4x4 grid of 16x16x32 bf16 MFMAs, K=64 in two k-steps.
//
// v2 epilogue: per-wave LDS transpose of the result tile. The raw MFMA C
// layout scatters a wave's store instruction over 16 rows x 64B (half-line
// segments; 256 half-line transactions/wave — this was the 2.2 TB/s
// bottleneck, invariant under v0->v1's instruction-count change). After the
// LDS round-trip each global_store_dwordx4 covers 4 rows x 256B full-line
// segments. Two 32-row passes keep LDS at 8KB/wave (32KB/block). f32x4
// units are XOR-swizzled (u ^= row&15) so both LDS phases are at the
// structural bank minimum. Stores are nontemporal: the 512 MiB out stream
// shouldn't evict the 3 MiB xb/yb panels from L2.
__global__ __launch_bounds__(256) void cdist_mfma_kernel(
    const unsigned short* __restrict__ xb, const unsigned short* __restrict__ yb,
    const float* __restrict__ xn, const float* __restrict__ yn,
    float* __restrict__ out, int Ncols) {
  int ybase = blockIdx.x * 128;   // y rows = out columns
  int xbase = blockIdx.y * 128;   // x rows = out rows
  int tid = threadIdx.x, wave = tid >> 6, lane = tid & 63;
  int quad = lane >> 4, l16 = lane & 15;
  int wy = (wave >> 1) * 64;      // wave offset along y (MFMA-M)
  int wx = (wave & 1) * 64;       // wave offset along x (MFMA-N)

  __shared__ float lds[4][2048];  // 8 KB per wave: 32 rows x 64 cols, swizzled

  const short* yp = (const short*)yb;
  const short* xp = (const short*)xb;
  int arow = ybase + wy + l16;    // A fragment rows come from y
  int brow = xbase + wx + l16;    // B fragment rows come from x
  int koff = quad * 8;

  bf16x8 a[2][4], b[2][4];
  #pragma unroll
  for (int i = 0; i < 4; i++) {
    const short* ap = yp + (size_t)(arow + i * 16) * DDIM + koff;
    const short* bp = xp + (size_t)(brow + i * 16) * DDIM + koff;
    a[0][i] = *(const bf16x8*)(ap);
    a[1][i] = *(const bf16x8*)(ap + 32);
    b[0][i] = *(const bf16x8*)(bp);
    b[1][i] = *(const bf16x8*)(bp + 32);
  }

  f32x4 acc[4][4] = {};
  #pragma unroll
  for (int ks = 0; ks < 2; ks++)
    #pragma unroll
    for (int i = 0; i < 4; i++)
      #pragma unroll
      for (int j = 0; j < 4; j++)
        acc[i][j] = __builtin_amdgcn_mfma_f32_16x16x32_bf16(
            a[ks][i], b[ks][j], acc[i][j], 0, 0, 0);

  // acc[i][j][r] = dot(y[ybase+wy+i*16+quad*4+r], x[xbase+wx+j*16+l16]).
  float* W = &lds[wave][0];
  #pragma unroll
  for (int p = 0; p < 2; p++) {
    // -- write phase: d = sqrt(max(xn+yn-2*dot,0)) into swizzled LDS --
    #pragma unroll
    for (int jj = 0; jj < 2; jj++) {
      int j = p * 2 + jj;
      int row = jj * 16 + l16;                  // wave-local x row, 0..31
      float xv = xn[xbase + wx + j * 16 + l16];
      #pragma unroll
      for (int i = 0; i < 4; i++) {
        int u = i * 4 + quad;                   // f32x4 unit index, 0..15
        int usw = u ^ (row & 15);
        float4 yv = *(const float4*)(yn + ybase + wy + i * 16 + quad * 4);
        f32x4 d;
        d[0] = sqrtf(fmaxf(xv + yv.x - 2.0f * acc[i][j][0], 0.0f));
        d[1] = sqrtf(fmaxf(xv + yv.y - 2.0f * acc[i][j][1], 0.0f));
        d[2] = sqrtf(fmaxf(xv + yv.z - 2.0f * acc[i][j][2], 0.0f));
        d[3] = sqrtf(fmaxf(xv + yv.w - 2.0f * acc[i][j][3], 0.0f));
        *(f32x4*)(W + row * 64 + 4 * usw) = d;
      }
    }
    // -- read phase: row-major, 256B-contiguous per row -- (wave-private
    // region: in-order per-wave DS pipe means no barrier needed)
    #pragma unroll
    for (int rr = 0; rr < 8; rr++) {
      int row = rr * 4 + quad;                  // 0..31
      int usw = l16 ^ (row & 15);
      f32x4 v = *(const f32x4*)(W + row * 64 + 4 * usw);
      size_t xrow = (size_t)(xbase + wx + p * 32 + row);
      int ycol = ybase + wy + l16 * 4;
      __builtin_nontemporal_store(v, (f32x4*)(out + xrow * Ncols + ycol));
    }
  }
}

// Correctness fallback if workspace is too small (shouldn't happen).
__global__ void cdist_naive_kernel(const float* __restrict__ x,
                                   const float* __restrict__ y,
                                   float* __restrict__ out, int M, int N) {
  size_t idx = (size_t)blockIdx.x * blockDim.x + threadIdx.x;
  size_t total = (size_t)M * N;
  if (idx >= total) return;
  int i = (int)(idx / N), j = (int)(idx % N);
  const float* xi = x + (size_t)i * DDIM;
  const float* yj = y + (size_t)j * DDIM;
  float acc = 0.f;
  #pragma unroll
  for (int k = 0; k < DDIM; k++) {
    float d = xi[k] - yj[k];
    acc += d * d;
  }
  out[idx] = sqrtf(acc);
}

extern "C" void kernel_launch(void* const* d_in, const int* in_sizes, int n_in,
                              void* d_out, int out_size, void* d_ws, size_t ws_size,
                              hipStream_t stream) {
  const float* x = (const float*)d_in[0];
  const float* y = (const float*)d_in[1];
  float* out = (float*)d_out;
  int M = in_sizes[0] / DDIM;   // 8192
  int N = in_sizes[1] / DDIM;   // 16384

  size_t xb_off = 0;
  size_t yb_off = xb_off + (size_t)M * DDIM * sizeof(unsigned short);
  size_t xn_off = yb_off + (size_t)N * DDIM * sizeof(unsigned short);
  size_t yn_off = xn_off + (size_t)M * sizeof(float);
  size_t need   = yn_off + (size_t)N * sizeof(float);

  if (ws_size < need || (M % 128) || (N % 128)) {
    size_t total = (size_t)M * N;
    int blocks = (int)((total + 255) / 256);
    cdist_naive_kernel<<<blocks, 256, 0, stream>>>(x, y, out, M, N);
    return;
  }

  unsigned short* xb = (unsigned short*)((char*)d_ws + xb_off);
  unsigned short* yb = (unsigned short*)((char*)d_ws + yb_off);
  float* xn = (float*)((char*)d_ws + xn_off);
  float* yn = (float*)((char*)d_ws + yn_off);

  int prep_blocks = (M + N) / 16;
  prep_kernel<<<prep_blocks, 256, 0, stream>>>(x, y, xb, yb, xn, yn, M, N);

  dim3 grid(N / 128, M / 128);
  cdist_mfma_kernel<<<grid, 256, 0, stream>>>(xb, yb, xn, yn, out, N);
}